// Round 1
// baseline (1316.034 us; speedup 1.0000x reference)
//
#include <hip/hip_runtime.h>

// StargazerGNN: 3-layer GCN + graph mean-pool + linear head.
// N=100000 nodes, E=1600000 edges, G=64 graphs, D=128.
// Strategy: build CSR-by-dst on device each call (no big-atomic scatter),
// aggregate per node without atomics, fp32 throughout.
// Workspace: ~111 MB (hA, Bm: N*128 f32 each; CSR arrays; small accumulators).

#define DHID 128
#define NGRAPH 64

__device__ __forceinline__ void fma4(float4& a, float s, const float4& w) {
  a.x = fmaf(s, w.x, a.x);
  a.y = fmaf(s, w.y, a.y);
  a.z = fmaf(s, w.z, a.z);
  a.w = fmaf(s, w.w, a.w);
}

// Degree count (int atomics, exact).
__global__ void k_deg(const int* __restrict__ src, const int* __restrict__ dst,
                      int* __restrict__ degout, int* __restrict__ degin, int E) {
  int e = blockIdx.x * 256 + threadIdx.x;
  if (e < E) {
    atomicAdd(&degout[src[e]], 1);
    atomicAdd(&degin[dst[e]], 1);
  }
}

// Assign CSR segment offsets (order nondeterministic but self-consistent),
// also count nodes per graph.
__global__ void k_off(const int* __restrict__ degin, const int* __restrict__ gid,
                      int* __restrict__ off, int* __restrict__ cur,
                      int* __restrict__ total, float* __restrict__ countsF, int N) {
  int n = blockIdx.x * 256 + threadIdx.x;
  if (n < N) {
    int d = degin[n];
    int o = atomicAdd(total, d);
    off[n] = o;
    cur[n] = o;
    atomicAdd(&countsF[gid[n]], 1.0f);
  }
}

// Scatter src indices into dst-grouped CSR.
__global__ void k_scatter(const int* __restrict__ src, const int* __restrict__ dst,
                          int* __restrict__ cur, int* __restrict__ eidx, int E) {
  int e = blockIdx.x * 256 + threadIdx.x;
  if (e < E) {
    int p = atomicAdd(&cur[dst[e]], 1);
    eidx[p] = src[e];
  }
}

// Layer-1 aggregation: agg1[n] = sum_{e:dst=n} deg_in[s] * norm_src[s].
__global__ void k_l1_agg(const int* __restrict__ degin, const int* __restrict__ degout,
                         const int* __restrict__ off, const int* __restrict__ eidx,
                         float* __restrict__ agg1, int N) {
  int n = blockIdx.x * 256 + threadIdx.x;
  if (n >= N) return;
  int o = off[n], c = degin[n];
  float acc = 0.0f;
  for (int i = 0; i < c; ++i) {
    int s = eidx[o + i];
    acc += (float)degin[s] * rsqrtf(fmaxf((float)degout[s], 1.0f));
  }
  agg1[n] = acc;
}

// Layer-1 node update: hA[n][j] = relu(agg1[n]*norm_dst[n]*W1[j] + b1[j]) * norm_src[n]
// (pre-scaled by norm_src for the next layer's gather). float4 over j.
__global__ void k_l1_h(const int* __restrict__ degin, const int* __restrict__ degout,
                       const float* __restrict__ agg1, const float* __restrict__ W1,
                       const float* __restrict__ b1, float* __restrict__ hA, int N) {
  int idx = blockIdx.x * 256 + threadIdx.x;  // over N*32 float4 slots
  int n = idx >> 5, c = idx & 31;
  if (n >= N) return;
  float nd = rsqrtf(fmaxf((float)degin[n], 1.0f));
  float ns = rsqrtf(fmaxf((float)degout[n], 1.0f));
  float x = agg1[n] * nd;
  float4 w = *(const float4*)(W1 + c * 4);
  float4 b = *(const float4*)(b1 + c * 4);
  float4 r;
  r.x = fmaxf(fmaf(x, w.x, b.x), 0.0f) * ns;
  r.y = fmaxf(fmaf(x, w.y, b.y), 0.0f) * ns;
  r.z = fmaxf(fmaf(x, w.z, b.z), 0.0f) * ns;
  r.w = fmaxf(fmaf(x, w.w, b.w), 0.0f) * ns;
  *((float4*)(hA + (size_t)n * DHID) + c) = r;
}

// CSR aggregation (the SpMM): Bm[n][:] = sum over incoming edges of hs[src][:].
// 8 nodes per 256-thread block; 32 lanes * float4 per node row.
__global__ void k_csr_agg(const float* __restrict__ hs, const int* __restrict__ off,
                          const int* __restrict__ degin, const int* __restrict__ eidx,
                          float* __restrict__ Bm, int N) {
  int node = blockIdx.x * 8 + (threadIdx.x >> 5);
  int lane = threadIdx.x & 31;
  if (node >= N) return;
  int o = off[node], c = degin[node];
  float4 acc = make_float4(0.f, 0.f, 0.f, 0.f);
  for (int i = 0; i < c; ++i) {
    int s = eidx[o + i];
    float4 v = *((const float4*)(hs + (size_t)s * DHID) + lane);
    acc.x += v.x; acc.y += v.y; acc.z += v.z; acc.w += v.w;
  }
  *((float4*)(Bm + (size_t)node * DHID) + lane) = acc;
}

// Dense 128x128 layer: hOut = relu((Bm * norm_dst) @ W + b) [* norm_src if MODE==0].
// MODE==1 additionally fuses the per-graph mean-pool numerator (segment-flush,
// graph_ids sorted). 32 nodes/block, 256 threads: thread = (ng:8 x 4 nodes, jg:32 x 4 cols).
template <int MODE>
__global__ __launch_bounds__(256) void k_mm(
    const float* __restrict__ Bm, const int* __restrict__ degin,
    const int* __restrict__ degout, const float* __restrict__ W,
    const float* __restrict__ bias, float* __restrict__ hOut,
    const int* __restrict__ gid, float* __restrict__ hg, int N) {
  __shared__ float xl[32][DHID];
  const int tid = threadIdx.x;
  const int base = blockIdx.x * 32;

  // Stage x = Bm_row * norm_dst into LDS (1024 float4 slots).
  for (int i = 0; i < 4; ++i) {
    int f = i * 256 + tid;
    int n = f >> 5, c = f & 31;
    int node = base + n;
    float4 v = make_float4(0.f, 0.f, 0.f, 0.f);
    if (node < N) {
      float nd = rsqrtf(fmaxf((float)degin[node], 1.0f));
      v = *((const float4*)(Bm + (size_t)node * DHID) + c);
      v.x *= nd; v.y *= nd; v.z *= nd; v.w *= nd;
    }
    *((float4*)&xl[n][0] + c) = v;
  }
  __syncthreads();

  const int jg = tid & 31;   // output column group (4 cols)
  const int ng = tid >> 5;   // node group (4 nodes)
  const float* wj = W + jg * 4;

  float4 acc[4];
#pragma unroll
  for (int i = 0; i < 4; ++i) acc[i] = make_float4(0.f, 0.f, 0.f, 0.f);

#pragma unroll 4
  for (int k = 0; k < DHID; k += 4) {
    float4 w0 = *(const float4*)(wj + (size_t)(k + 0) * DHID);
    float4 w1 = *(const float4*)(wj + (size_t)(k + 1) * DHID);
    float4 w2 = *(const float4*)(wj + (size_t)(k + 2) * DHID);
    float4 w3 = *(const float4*)(wj + (size_t)(k + 3) * DHID);
#pragma unroll
    for (int i = 0; i < 4; ++i) {
      float4 x = *(const float4*)&xl[ng * 4 + i][k];
      fma4(acc[i], x.x, w0);
      fma4(acc[i], x.y, w1);
      fma4(acc[i], x.z, w2);
      fma4(acc[i], x.w, w3);
    }
  }

  float4 bb = *(const float4*)(bias + jg * 4);

  if (MODE == 0) {
#pragma unroll
    for (int i = 0; i < 4; ++i) {
      int node = base + ng * 4 + i;
      if (node < N) {
        float ns = rsqrtf(fmaxf((float)degout[node], 1.0f));
        float4 r;
        r.x = fmaxf(acc[i].x + bb.x, 0.0f) * ns;
        r.y = fmaxf(acc[i].y + bb.y, 0.0f) * ns;
        r.z = fmaxf(acc[i].z + bb.z, 0.0f) * ns;
        r.w = fmaxf(acc[i].w + bb.w, 0.0f) * ns;
        *((float4*)(hOut + (size_t)node * DHID) + jg) = r;
      }
    }
  } else {
    // h3 (unscaled) back into LDS, then fused graph-mean-pool numerator.
    __syncthreads();
#pragma unroll
    for (int i = 0; i < 4; ++i) {
      int n = ng * 4 + i;
      float4 r;
      r.x = fmaxf(acc[i].x + bb.x, 0.0f);
      r.y = fmaxf(acc[i].y + bb.y, 0.0f);
      r.z = fmaxf(acc[i].z + bb.z, 0.0f);
      r.w = fmaxf(acc[i].w + bb.w, 0.0f);
      *((float4*)&xl[n][0] + jg) = r;
    }
    __syncthreads();
    if (tid < DHID) {
      float s = 0.0f;
      int gcur = gid[base];
      for (int n = 0; n < 32; ++n) {
        int node = base + n;
        if (node >= N) break;
        int g = gid[node];
        if (g != gcur) {
          atomicAdd(&hg[gcur * DHID + tid], s);
          s = 0.0f;
          gcur = g;
        }
        s += xl[n][tid];
      }
      atomicAdd(&hg[gcur * DHID + tid], s);
    }
  }
}

// Final head: out[g][c] = (hg[g][:] @ Wc[:,c]) / clip(counts[g],1) + bc[c].
__global__ void k_out(const float* __restrict__ hg, const float* __restrict__ countsF,
                      const float* __restrict__ Wc, const float* __restrict__ bc,
                      float* __restrict__ out) {
  int t = threadIdx.x;  // 128 = 64 graphs x 2 outputs
  int g = t >> 1, c = t & 1;
  float acc = 0.0f;
  for (int d = 0; d < DHID; ++d) acc = fmaf(hg[g * DHID + d], Wc[d * 2 + c], acc);
  out[t] = acc / fmaxf(countsF[g], 1.0f) + bc[c];
}

extern "C" void kernel_launch(void* const* d_in, const int* in_sizes, int n_in,
                              void* d_out, int out_size, void* d_ws, size_t ws_size,
                              hipStream_t stream) {
  const int* src = (const int*)d_in[0];
  const int* dst = (const int*)d_in[1];
  const int* gid = (const int*)d_in[2];
  const float* W1 = (const float*)d_in[3];
  const float* b1 = (const float*)d_in[4];
  const float* W2 = (const float*)d_in[5];
  const float* b2 = (const float*)d_in[6];
  const float* W3 = (const float*)d_in[7];
  const float* b3 = (const float*)d_in[8];
  const float* Wc = (const float*)d_in[9];
  const float* bc = (const float*)d_in[10];
  float* out = (float*)d_out;
  const int E = in_sizes[0];
  const int N = in_sizes[2];

  char* ws = (char*)d_ws;
  size_t o = 0;
  auto alloc = [&](size_t bytes) {
    void* p = ws + o;
    o += (bytes + 255) & ~(size_t)255;
    return p;
  };
  float* hA = (float*)alloc((size_t)N * DHID * 4);
  float* Bm = (float*)alloc((size_t)N * DHID * 4);
  size_t z0 = o;  // start of zero-init region
  int* degin = (int*)alloc((size_t)N * 4);
  int* degout = (int*)alloc((size_t)N * 4);
  float* hg = (float*)alloc((size_t)NGRAPH * DHID * 4);
  float* countsF = (float*)alloc((size_t)NGRAPH * 4);
  int* total = (int*)alloc(4);
  size_t z1 = o;  // end of zero-init region
  float* agg1 = (float*)alloc((size_t)N * 4);
  int* off = (int*)alloc((size_t)N * 4);
  int* cur = (int*)alloc((size_t)N * 4);
  int* eidx = (int*)alloc((size_t)E * 4);
  (void)ws_size;  // ~111 MB used; assumed available

  hipMemsetAsync(ws + z0, 0, z1 - z0, stream);

  k_deg<<<(E + 255) / 256, 256, 0, stream>>>(src, dst, degout, degin, E);
  k_off<<<(N + 255) / 256, 256, 0, stream>>>(degin, gid, off, cur, total, countsF, N);
  k_scatter<<<(E + 255) / 256, 256, 0, stream>>>(src, dst, cur, eidx, E);
  k_l1_agg<<<(N + 255) / 256, 256, 0, stream>>>(degin, degout, off, eidx, agg1, N);
  k_l1_h<<<((size_t)N * 32 + 255) / 256, 256, 0, stream>>>(degin, degout, agg1, W1, b1, hA, N);
  // Layer 2
  k_csr_agg<<<(N + 7) / 8, 256, 0, stream>>>(hA, off, degin, eidx, Bm, N);
  k_mm<0><<<(N + 31) / 32, 256, 0, stream>>>(Bm, degin, degout, W2, b2, hA, gid, hg, N);
  // Layer 3 (+ fused mean-pool numerator)
  k_csr_agg<<<(N + 7) / 8, 256, 0, stream>>>(hA, off, degin, eidx, Bm, N);
  k_mm<1><<<(N + 31) / 32, 256, 0, stream>>>(Bm, degin, degout, W3, b3, nullptr, gid, hg, N);
  // Head
  k_out<<<1, 128, 0, stream>>>(hg, countsF, Wc, bc, out);
}

// Round 2
// 668.579 us; speedup vs baseline: 1.9684x; 1.9684x over previous
//
#include <hip/hip_runtime.h>

// StargazerGNN: 3-layer GCN + graph mean-pool + linear head.
// N=100000 nodes, E=1600000 edges, G=64 graphs, D=128.
// R1 fix: k_off's single-address atomicAdd(total) serialized 100K atomics
// (652 us, 50% of runtime). Replaced with block-level shfl scan + 1 atomic
// per block; countsF via LDS reduction (1 global atomic per block*graph).

#define DHID 128
#define NGRAPH 64

__device__ __forceinline__ void fma4(float4& a, float s, const float4& w) {
  a.x = fmaf(s, w.x, a.x);
  a.y = fmaf(s, w.y, a.y);
  a.z = fmaf(s, w.z, a.z);
  a.w = fmaf(s, w.w, a.w);
}

// Degree count (int atomics, distributed over N addresses).
__global__ void k_deg(const int* __restrict__ src, const int* __restrict__ dst,
                      int* __restrict__ degout, int* __restrict__ degin, int E) {
  int e = blockIdx.x * 256 + threadIdx.x;
  if (e < E) {
    atomicAdd(&degout[src[e]], 1);
    atomicAdd(&degin[dst[e]], 1);
  }
}

// CSR offsets via hierarchical scan: wave64 inclusive scan -> per-wave sums ->
// ONE global atomic per block -> exclusive per-thread offset. Graph node
// counts via LDS float atomics, flushed once per block.
__global__ __launch_bounds__(256) void k_off(
    const int* __restrict__ degin, const int* __restrict__ gid,
    int* __restrict__ off, int* __restrict__ cur,
    int* __restrict__ total, float* __restrict__ countsF, int N) {
  __shared__ int wsum[4];
  __shared__ float lcounts[NGRAPH];
  const int tid = threadIdx.x;
  const int n = blockIdx.x * 256 + tid;
  const int lane = tid & 63;
  const int wave = tid >> 6;

  int d = (n < N) ? degin[n] : 0;
  int val = d;  // inclusive scan within wave64
#pragma unroll
  for (int s = 1; s < 64; s <<= 1) {
    int up = __shfl_up(val, s, 64);
    if (lane >= s) val += up;
  }
  if (lane == 63) wsum[wave] = val;
  if (tid < NGRAPH) lcounts[tid] = 0.0f;
  __syncthreads();

  if (tid == 0) {
    int s0 = wsum[0], s1 = wsum[1], s2 = wsum[2], s3 = wsum[3];
    int base = atomicAdd(total, s0 + s1 + s2 + s3);
    wsum[0] = base;
    wsum[1] = base + s0;
    wsum[2] = base + s0 + s1;
    wsum[3] = base + s0 + s1 + s2;
  }
  __syncthreads();

  if (n < N) {
    int o = wsum[wave] + (val - d);  // exclusive offset
    off[n] = o;
    cur[n] = o;
    atomicAdd(&lcounts[gid[n]], 1.0f);  // LDS atomic (fast)
  }
  __syncthreads();
  if (tid < NGRAPH) {
    float c = lcounts[tid];
    if (c != 0.0f) atomicAdd(&countsF[tid], c);
  }
}

// Scatter src indices into dst-grouped CSR.
__global__ void k_scatter(const int* __restrict__ src, const int* __restrict__ dst,
                          int* __restrict__ cur, int* __restrict__ eidx, int E) {
  int e = blockIdx.x * 256 + threadIdx.x;
  if (e < E) {
    int p = atomicAdd(&cur[dst[e]], 1);
    eidx[p] = src[e];
  }
}

// Layer-1 aggregation: agg1[n] = sum_{e:dst=n} deg_in[s] * norm_src[s].
__global__ void k_l1_agg(const int* __restrict__ degin, const int* __restrict__ degout,
                         const int* __restrict__ off, const int* __restrict__ eidx,
                         float* __restrict__ agg1, int N) {
  int n = blockIdx.x * 256 + threadIdx.x;
  if (n >= N) return;
  int o = off[n], c = degin[n];
  float acc = 0.0f;
  for (int i = 0; i < c; ++i) {
    int s = eidx[o + i];
    acc += (float)degin[s] * rsqrtf(fmaxf((float)degout[s], 1.0f));
  }
  agg1[n] = acc;
}

// Layer-1 node update: hA[n][j] = relu(agg1[n]*norm_dst[n]*W1[j] + b1[j]) * norm_src[n]
// (pre-scaled by norm_src for the next layer's gather). float4 over j.
__global__ void k_l1_h(const int* __restrict__ degin, const int* __restrict__ degout,
                       const float* __restrict__ agg1, const float* __restrict__ W1,
                       const float* __restrict__ b1, float* __restrict__ hA, int N) {
  int idx = blockIdx.x * 256 + threadIdx.x;  // over N*32 float4 slots
  int n = idx >> 5, c = idx & 31;
  if (n >= N) return;
  float nd = rsqrtf(fmaxf((float)degin[n], 1.0f));
  float ns = rsqrtf(fmaxf((float)degout[n], 1.0f));
  float x = agg1[n] * nd;
  float4 w = *(const float4*)(W1 + c * 4);
  float4 b = *(const float4*)(b1 + c * 4);
  float4 r;
  r.x = fmaxf(fmaf(x, w.x, b.x), 0.0f) * ns;
  r.y = fmaxf(fmaf(x, w.y, b.y), 0.0f) * ns;
  r.z = fmaxf(fmaf(x, w.z, b.z), 0.0f) * ns;
  r.w = fmaxf(fmaf(x, w.w, b.w), 0.0f) * ns;
  *((float4*)(hA + (size_t)n * DHID) + c) = r;
}

// CSR aggregation (the SpMM): Bm[n][:] = sum over incoming edges of hs[src][:].
// 8 nodes per 256-thread block; 32 lanes * float4 per node row.
__global__ void k_csr_agg(const float* __restrict__ hs, const int* __restrict__ off,
                          const int* __restrict__ degin, const int* __restrict__ eidx,
                          float* __restrict__ Bm, int N) {
  int node = blockIdx.x * 8 + (threadIdx.x >> 5);
  int lane = threadIdx.x & 31;
  if (node >= N) return;
  int o = off[node], c = degin[node];
  float4 acc = make_float4(0.f, 0.f, 0.f, 0.f);
  for (int i = 0; i < c; ++i) {
    int s = eidx[o + i];
    float4 v = *((const float4*)(hs + (size_t)s * DHID) + lane);
    acc.x += v.x; acc.y += v.y; acc.z += v.z; acc.w += v.w;
  }
  *((float4*)(Bm + (size_t)node * DHID) + lane) = acc;
}

// Dense 128x128 layer: hOut = relu((Bm * norm_dst) @ W + b) [* norm_src if MODE==0].
// MODE==1 additionally fuses the per-graph mean-pool numerator (segment-flush,
// graph_ids sorted). 32 nodes/block, 256 threads: thread = (ng:8 x 4 nodes, jg:32 x 4 cols).
template <int MODE>
__global__ __launch_bounds__(256) void k_mm(
    const float* __restrict__ Bm, const int* __restrict__ degin,
    const int* __restrict__ degout, const float* __restrict__ W,
    const float* __restrict__ bias, float* __restrict__ hOut,
    const int* __restrict__ gid, float* __restrict__ hg, int N) {
  __shared__ float xl[32][DHID];
  const int tid = threadIdx.x;
  const int base = blockIdx.x * 32;

  // Stage x = Bm_row * norm_dst into LDS (1024 float4 slots).
  for (int i = 0; i < 4; ++i) {
    int f = i * 256 + tid;
    int n = f >> 5, c = f & 31;
    int node = base + n;
    float4 v = make_float4(0.f, 0.f, 0.f, 0.f);
    if (node < N) {
      float nd = rsqrtf(fmaxf((float)degin[node], 1.0f));
      v = *((const float4*)(Bm + (size_t)node * DHID) + c);
      v.x *= nd; v.y *= nd; v.z *= nd; v.w *= nd;
    }
    *((float4*)&xl[n][0] + c) = v;
  }
  __syncthreads();

  const int jg = tid & 31;   // output column group (4 cols)
  const int ng = tid >> 5;   // node group (4 nodes)
  const float* wj = W + jg * 4;

  float4 acc[4];
#pragma unroll
  for (int i = 0; i < 4; ++i) acc[i] = make_float4(0.f, 0.f, 0.f, 0.f);

#pragma unroll 4
  for (int k = 0; k < DHID; k += 4) {
    float4 w0 = *(const float4*)(wj + (size_t)(k + 0) * DHID);
    float4 w1 = *(const float4*)(wj + (size_t)(k + 1) * DHID);
    float4 w2 = *(const float4*)(wj + (size_t)(k + 2) * DHID);
    float4 w3 = *(const float4*)(wj + (size_t)(k + 3) * DHID);
#pragma unroll
    for (int i = 0; i < 4; ++i) {
      float4 x = *(const float4*)&xl[ng * 4 + i][k];
      fma4(acc[i], x.x, w0);
      fma4(acc[i], x.y, w1);
      fma4(acc[i], x.z, w2);
      fma4(acc[i], x.w, w3);
    }
  }

  float4 bb = *(const float4*)(bias + jg * 4);

  if (MODE == 0) {
#pragma unroll
    for (int i = 0; i < 4; ++i) {
      int node = base + ng * 4 + i;
      if (node < N) {
        float ns = rsqrtf(fmaxf((float)degout[node], 1.0f));
        float4 r;
        r.x = fmaxf(acc[i].x + bb.x, 0.0f) * ns;
        r.y = fmaxf(acc[i].y + bb.y, 0.0f) * ns;
        r.z = fmaxf(acc[i].z + bb.z, 0.0f) * ns;
        r.w = fmaxf(acc[i].w + bb.w, 0.0f) * ns;
        *((float4*)(hOut + (size_t)node * DHID) + jg) = r;
      }
    }
  } else {
    // h3 (unscaled) back into LDS, then fused graph-mean-pool numerator.
    __syncthreads();
#pragma unroll
    for (int i = 0; i < 4; ++i) {
      int n = ng * 4 + i;
      float4 r;
      r.x = fmaxf(acc[i].x + bb.x, 0.0f);
      r.y = fmaxf(acc[i].y + bb.y, 0.0f);
      r.z = fmaxf(acc[i].z + bb.z, 0.0f);
      r.w = fmaxf(acc[i].w + bb.w, 0.0f);
      *((float4*)&xl[n][0] + jg) = r;
    }
    __syncthreads();
    if (tid < DHID) {
      float s = 0.0f;
      int gcur = gid[base];
      for (int n = 0; n < 32; ++n) {
        int node = base + n;
        if (node >= N) break;
        int g = gid[node];
        if (g != gcur) {
          atomicAdd(&hg[gcur * DHID + tid], s);
          s = 0.0f;
          gcur = g;
        }
        s += xl[n][tid];
      }
      atomicAdd(&hg[gcur * DHID + tid], s);
    }
  }
}

// Final head: out[g][c] = (hg[g][:] @ Wc[:,c]) / clip(counts[g],1) + bc[c].
__global__ void k_out(const float* __restrict__ hg, const float* __restrict__ countsF,
                      const float* __restrict__ Wc, const float* __restrict__ bc,
                      float* __restrict__ out) {
  int t = threadIdx.x;  // 128 = 64 graphs x 2 outputs
  int g = t >> 1, c = t & 1;
  float acc = 0.0f;
  for (int d = 0; d < DHID; ++d) acc = fmaf(hg[g * DHID + d], Wc[d * 2 + c], acc);
  out[t] = acc / fmaxf(countsF[g], 1.0f) + bc[c];
}

extern "C" void kernel_launch(void* const* d_in, const int* in_sizes, int n_in,
                              void* d_out, int out_size, void* d_ws, size_t ws_size,
                              hipStream_t stream) {
  const int* src = (const int*)d_in[0];
  const int* dst = (const int*)d_in[1];
  const int* gid = (const int*)d_in[2];
  const float* W1 = (const float*)d_in[3];
  const float* b1 = (const float*)d_in[4];
  const float* W2 = (const float*)d_in[5];
  const float* b2 = (const float*)d_in[6];
  const float* W3 = (const float*)d_in[7];
  const float* b3 = (const float*)d_in[8];
  const float* Wc = (const float*)d_in[9];
  const float* bc = (const float*)d_in[10];
  float* out = (float*)d_out;
  const int E = in_sizes[0];
  const int N = in_sizes[2];

  char* ws = (char*)d_ws;
  size_t o = 0;
  auto alloc = [&](size_t bytes) {
    void* p = ws + o;
    o += (bytes + 255) & ~(size_t)255;
    return p;
  };
  float* hA = (float*)alloc((size_t)N * DHID * 4);
  float* Bm = (float*)alloc((size_t)N * DHID * 4);
  size_t z0 = o;  // start of zero-init region
  int* degin = (int*)alloc((size_t)N * 4);
  int* degout = (int*)alloc((size_t)N * 4);
  float* hg = (float*)alloc((size_t)NGRAPH * DHID * 4);
  float* countsF = (float*)alloc((size_t)NGRAPH * 4);
  int* total = (int*)alloc(4);
  size_t z1 = o;  // end of zero-init region
  float* agg1 = (float*)alloc((size_t)N * 4);
  int* off = (int*)alloc((size_t)N * 4);
  int* cur = (int*)alloc((size_t)N * 4);
  int* eidx = (int*)alloc((size_t)E * 4);
  (void)ws_size;  // ~111 MB used; assumed available

  hipMemsetAsync(ws + z0, 0, z1 - z0, stream);

  k_deg<<<(E + 255) / 256, 256, 0, stream>>>(src, dst, degout, degin, E);
  k_off<<<(N + 255) / 256, 256, 0, stream>>>(degin, gid, off, cur, total, countsF, N);
  k_scatter<<<(E + 255) / 256, 256, 0, stream>>>(src, dst, cur, eidx, E);
  k_l1_agg<<<(N + 255) / 256, 256, 0, stream>>>(degin, degout, off, eidx, agg1, N);
  k_l1_h<<<((size_t)N * 32 + 255) / 256, 256, 0, stream>>>(degin, degout, agg1, W1, b1, hA, N);
  // Layer 2
  k_csr_agg<<<(N + 7) / 8, 256, 0, stream>>>(hA, off, degin, eidx, Bm, N);
  k_mm<0><<<(N + 31) / 32, 256, 0, stream>>>(Bm, degin, degout, W2, b2, hA, gid, hg, N);
  // Layer 3 (+ fused mean-pool numerator)
  k_csr_agg<<<(N + 7) / 8, 256, 0, stream>>>(hA, off, degin, eidx, Bm, N);
  k_mm<1><<<(N + 31) / 32, 256, 0, stream>>>(Bm, degin, degout, W3, b3, nullptr, gid, hg, N);
  // Head
  k_out<<<1, 128, 0, stream>>>(hg, countsF, Wc, bc, out);
}